// Round 3
// baseline (6272.413 us; speedup 1.0000x reference)
//
#include <hip/hip_runtime.h>
#include <cstdint>
#include <cstddef>

#define Bsz 64
#define Tn  512
#define Dn  512
#define Hn  512
#define NG  2048        // 4*H
#define GWG 32          // workgroups per direction
#define NCOL 16         // h-columns per WG
#define SENTI 0x7f7f7f7fu   // bf16 0x7F7F = 3.3e38, impossible for |h|<=1

typedef __attribute__((ext_vector_type(8))) short short8;
typedef __attribute__((ext_vector_type(4))) float f32x4;
typedef __attribute__((ext_vector_type(4))) unsigned int u32x4;

union FragU { u32x4 v; short8 s; };

__device__ __forceinline__ unsigned short f2bf(float f) {
  union { float f; uint32_t u; } v; v.f = f;
  uint32_t u = v.u;
  uint32_t r = (u + 0x7fffu + ((u >> 16) & 1u)) >> 16;
  return (unsigned short)r;
}

__device__ __forceinline__ float sigm(float x) { return 1.0f / (1.0f + __expf(-x)); }
__device__ __forceinline__ float tanh_f(float x) { return 1.0f - 2.0f / (__expf(2.0f * x) + 1.0f); }

// ---------------- prep kernel 1: cast x fp32 -> bf16 ----------------
__global__ __launch_bounds__(256) void cast_x_kernel(const float* __restrict__ x,
                                                     unsigned short* __restrict__ xb) {
  size_t i = ((size_t)blockIdx.x * 256 + threadIdx.x) * 8;
  f32x4 a = *(const f32x4*)(x + i);
  f32x4 b = *(const f32x4*)(x + i + 4);
  short8 r;
  r[0] = (short)f2bf(a[0]); r[1] = (short)f2bf(a[1]);
  r[2] = (short)f2bf(a[2]); r[3] = (short)f2bf(a[3]);
  r[4] = (short)f2bf(b[0]); r[5] = (short)f2bf(b[1]);
  r[6] = (short)f2bf(b[2]); r[7] = (short)f2bf(b[3]);
  *(short8*)(xb + i) = r;
}

// ---------------- prep kernel 2: swizzle weights into MFMA B-fragment order ----------------
// frag layout (bf16): [dir(2)][wg(32)][nt(4)][kc(16)][lane(64)][j(8)]
//   n = nt*512 + wg*16 + (lane&15);  k = kc*32 + (lane>>4)*8 + j
__global__ __launch_bounds__(256) void swizzle_w_kernel(
    const float* __restrict__ Wfk, const float* __restrict__ Wfr,
    const float* __restrict__ Wbk, const float* __restrict__ Wbr,
    unsigned short* __restrict__ wkf, unsigned short* __restrict__ wrf)
{
  int idx = blockIdx.x * 256 + threadIdx.x;   // 0 .. 262143
  int arr  = blockIdx.y;                       // 0 = Wk, 1 = Wr
  int lane = idx & 63;
  int kc   = (idx >> 6) & 15;
  int nt   = (idx >> 10) & 3;
  int wg   = (idx >> 12) & 31;
  int dir  = (idx >> 17) & 1;
  const float* W = arr ? (dir ? Wbr : Wfr) : (dir ? Wbk : Wfk);
  unsigned short* dst = (arr ? wrf : wkf) + (size_t)idx * 8;
  int n  = nt * 512 + wg * NCOL + (lane & 15);
  int k0 = kc * 32 + ((lane >> 4) & 3) * 8;
#pragma unroll
  for (int j = 0; j < 8; ++j) dst[j] = f2bf(W[(size_t)(k0 + j) * NG + n]);
}

// ---------------- main persistent LSTM kernel ----------------
// h exchanged via a sentinel-validated ring: hbuf[dir(2)][slot(8)][mt(4)][kc(16)][lane(64)][j(8)] bf16.
// Step t publishes into slot (t+1)&7; consumers poll slot t&7 directly (data-as-flag,
// dword==0x7f7f7f7f means "not yet written"); producer re-sentinels slot (t+5)&7.
// No flags, no producer-side waitcnt, no __syncthreads in the t-loop.
__global__ __launch_bounds__(256, 1) void lstm_main_kernel(
    const unsigned short* __restrict__ xb,
    const unsigned short* __restrict__ wkf,
    const unsigned short* __restrict__ wrf,
    const float* __restrict__ bias_f, const float* __restrict__ bias_b,
    unsigned short* __restrict__ hbuf,
    float* __restrict__ out)
{
  const int wg   = blockIdx.x;     // 0..31 (h-column slice)
  const int dir  = blockIdx.y;     // 0 fwd, 1 bwd
  const int tid  = threadIdx.x;
  const int lane = tid & 63;
  const int wv   = tid >> 6;       // wave id = m-tile (16 batch rows)
  const int quad = lane >> 4;
  const int col  = lane & 15;

  extern __shared__ char smem[];                  // 128 KiB dynamic
  short8* wr_lds = (short8*)smem;                 // 64 KiB Wr fragments
  short8* wk_lds = (short8*)(smem + 65536);       // 64 KiB Wk fragments

  {
    const short8* srcR = (const short8*)wrf + (size_t)(dir * GWG + wg) * 4096;
    const short8* srcK = (const short8*)wkf + (size_t)(dir * GWG + wg) * 4096;
    for (int i = tid; i < 4096; i += 256) { wr_lds[i] = srcR[i]; wk_lds[i] = srcK[i]; }
  }

  const float* bias = dir ? bias_b : bias_f;
  float bz[4];
#pragma unroll
  for (int g = 0; g < 4; ++g) bz[g] = bias[g * 512 + wg * NCOL + col];

  float cst[4] = {0.f, 0.f, 0.f, 0.f};

  const int am = wv * 16 + col;              // batch row for A-fragment loads
  unsigned short* ring = hbuf + (size_t)dir * (8 * 32768);   // 8 slots x 64 KiB

  // producer h-store constants (fragment-layout address for this lane's column pair)
  const int kcW = wg >> 1;
  const int c0  = col & ~1;
  const int qd2 = (((wg & 1) << 4) + c0) >> 3;   // k-quad of this column pair
  const int j2  = c0 & 7;
  const int r0  = (col & 1) << 1;                 // even lane stores r=0,1; odd r=2,3
  const int eBase = (((wv * 16 + kcW) * 64 + qd2 * 16 + quad * 4 + r0) * 8 + j2) >> 1;

  // x-row register prefetch (one step ahead; keeps the x-GEMM free of global loads)
  short8 xr[16];
  {
    const int tx0 = dir ? (Tn - 1) : 0;
    const short8* xrow = (const short8*)(xb + ((size_t)am * Tn + tx0) * Dn);
#pragma unroll
    for (int kc = 0; kc < 16; ++kc) xr[kc] = xrow[kc * 4 + quad];
  }

  __syncthreads();   // wr_lds/wk_lds ready (only barrier outside the t-loop)

#define HL(idx, base, offs) \
  asm volatile("global_load_dwordx4 %0, %1, off" offs " sc0 sc1" \
               : "=v"(hfr[idx].v) : "v"(base))
#define HISSUE() do { \
    const char* b0_ = hb; const char* b1_ = hb + 4096; \
    const char* b2_ = hb + 8192; const char* b3_ = hb + 12288; \
    HL(0,  b0_, "");               HL(1,  b0_, " offset:1024"); \
    HL(2,  b0_, " offset:2048");   HL(3,  b0_, " offset:3072"); \
    HL(4,  b1_, "");               HL(5,  b1_, " offset:1024"); \
    HL(6,  b1_, " offset:2048");   HL(7,  b1_, " offset:3072"); \
    HL(8,  b2_, "");               HL(9,  b2_, " offset:1024"); \
    HL(10, b2_, " offset:2048");   HL(11, b2_, " offset:3072"); \
    HL(12, b3_, "");               HL(13, b3_, " offset:1024"); \
    HL(14, b3_, " offset:2048");   HL(15, b3_, " offset:3072"); \
  } while (0)

  for (int t = 0; t < Tn; ++t) {
    const int tx = dir ? (Tn - 1 - t) : t;
    f32x4 a0 = {0.f,0.f,0.f,0.f}, a1 = {0.f,0.f,0.f,0.f};
    f32x4 a2 = {0.f,0.f,0.f,0.f}, a3 = {0.f,0.f,0.f,0.f};

    // ---- pre-issue this step's h loads (slot t&7 holds step t-1; slot 0 starts zeroed) ----
    FragU hfr[16];
    const char* hb = (const char*)ring + (size_t)(t & 7) * 65536
                   + ((size_t)(wv * 16) * 64 + lane) * 16;
    HISSUE();

    // ---- x-half (LDS weights + prefetched x regs: no global loads, overlaps h latency) ----
#pragma unroll 4
    for (int kc = 0; kc < 16; ++kc) {
      short8 a = xr[kc];
      a0 = __builtin_amdgcn_mfma_f32_16x16x32_bf16(a, wk_lds[(0*16+kc)*64 + lane], a0, 0,0,0);
      a1 = __builtin_amdgcn_mfma_f32_16x16x32_bf16(a, wk_lds[(1*16+kc)*64 + lane], a1, 0,0,0);
      a2 = __builtin_amdgcn_mfma_f32_16x16x32_bf16(a, wk_lds[(2*16+kc)*64 + lane], a2, 0,0,0);
      a3 = __builtin_amdgcn_mfma_f32_16x16x32_bf16(a, wk_lds[(3*16+kc)*64 + lane], a3, 0,0,0);
    }

    // ---- prefetch next step's x-row into registers (consumed next iteration) ----
    if (t < Tn - 1) {
      const int txn = dir ? (Tn - 2 - t) : (t + 1);
      const short8* xrow = (const short8*)(xb + ((size_t)am * Tn + txn) * Dn);
#pragma unroll
      for (int kc = 0; kc < 16; ++kc) xr[kc] = xrow[kc * 4 + quad];
    }

    // ---- sentinel poll: retry until every dword of every fragment is real h data ----
    for (;;) {
      asm volatile("s_waitcnt vmcnt(0)" ::: "memory");
      __builtin_amdgcn_sched_barrier(0);
      int ok = 1;
#pragma unroll
      for (int kc = 0; kc < 16; ++kc) {
        ok &= (hfr[kc].v[0] != SENTI);
        ok &= (hfr[kc].v[1] != SENTI);
        ok &= (hfr[kc].v[2] != SENTI);
        ok &= (hfr[kc].v[3] != SENTI);
      }
      if (__ballot(!ok) == 0ull) break;
      HISSUE();
    }

    // ---- h-half MFMAs (Wr from LDS; hfr already in registers from the poll) ----
#pragma unroll
    for (int kc = 0; kc < 16; ++kc) {
      short8 a = hfr[kc].s;
      a0 = __builtin_amdgcn_mfma_f32_16x16x32_bf16(a, wr_lds[(0*16+kc)*64 + lane], a0, 0,0,0);
      a1 = __builtin_amdgcn_mfma_f32_16x16x32_bf16(a, wr_lds[(1*16+kc)*64 + lane], a1, 0,0,0);
      a2 = __builtin_amdgcn_mfma_f32_16x16x32_bf16(a, wr_lds[(2*16+kc)*64 + lane], a2, 0,0,0);
      a3 = __builtin_amdgcn_mfma_f32_16x16x32_bf16(a, wr_lds[(3*16+kc)*64 + lane], a3, 0,0,0);
    }

    // ---- gates ----
    float hv[4];
#pragma unroll
    for (int r = 0; r < 4; ++r) {
      float zi = a0[r] + bz[0];
      float zf = a1[r] + bz[1];
      float zg = a2[r] + bz[2];
      float zo = a3[r] + bz[3];
      float ig = sigm(zi);
      float fg = sigm(zf);
      float gg = tanh_f(zg);
      float og = sigm(zo);
      float c  = fg * cst[r] + ig * gg;
      cst[r] = c;
      hv[r] = og * tanh_f(c);
    }

    // ---- publish h in fragment layout (pack column pair via one shfl_xor) ----
    // No waitcnt / no flag: consumers validate the data itself. The poll loop's
    // vmcnt(0) above (executed every step) guarantees last step's clear stores are
    // acked at the coherent point before this publish issues (ring-reuse safety).
    unsigned short hb16[4];
#pragma unroll
    for (int r = 0; r < 4; ++r) hb16[r] = f2bf(hv[r]);
    uint32_t msg = (col & 1) ? ((uint32_t)hb16[0] | ((uint32_t)hb16[1] << 16))
                             : ((uint32_t)hb16[2] | ((uint32_t)hb16[3] << 16));
    uint32_t got = (uint32_t)__shfl_xor((int)msg, 1);
    uint32_t pkA, pkB;
    if ((col & 1) == 0) {      // store r=0,1; mine is low (even col)
      pkA = (uint32_t)hb16[0] | ((got & 0xffffu) << 16);
      pkB = (uint32_t)hb16[1] | ((got >> 16) << 16);
    } else {                   // store r=2,3; partner is low
      pkA = (got & 0xffffu) | ((uint32_t)hb16[2] << 16);
      pkB = (got >> 16)     | ((uint32_t)hb16[3] << 16);
    }
    uint32_t* hc = (uint32_t*)((char*)ring + (size_t)((t + 1) & 7) * 65536);
    uint32_t* hx = (uint32_t*)((char*)ring + (size_t)((t + 5) & 7) * 65536);
    __hip_atomic_store(hc + eBase,     pkA, __ATOMIC_RELAXED, __HIP_MEMORY_SCOPE_AGENT);
    __hip_atomic_store(hc + eBase + 4, pkB, __ATOMIC_RELAXED, __HIP_MEMORY_SCOPE_AGENT);
    // re-sentinel slot (t+5)&7: destroys step t-4 data (all readers provably done),
    // arms the slot for step t+4's consumers.
    __hip_atomic_store(hx + eBase,     SENTI, __ATOMIC_RELAXED, __HIP_MEMORY_SCOPE_AGENT);
    __hip_atomic_store(hx + eBase + 4, SENTI, __ATOMIC_RELAXED, __HIP_MEMORY_SCOPE_AGENT);

    // ---- out stores (off critical path) ----
#pragma unroll
    for (int r = 0; r < 4; ++r) {
      const int b = wv * 16 + quad * 4 + r;
      out[((size_t)b * Tn + tx) * (2 * Hn) + dir * Hn + wg * NCOL + col] = hv[r];
      if (t == Tn - 1)
        out[(size_t)Bsz * Tn * (2 * Hn) + (size_t)b * (2 * Hn) + dir * Hn + wg * NCOL + col] = hv[r];
    }
  }
#undef HISSUE
#undef HL
}

// ---------------- launch ----------------
extern "C" void kernel_launch(void* const* d_in, const int* in_sizes, int n_in,
                              void* d_out, int out_size, void* d_ws, size_t ws_size,
                              hipStream_t stream) {
  const float* x   = (const float*)d_in[0];
  const float* Wfk = (const float*)d_in[1];
  const float* Wfr = (const float*)d_in[2];
  const float* bf_ = (const float*)d_in[3];
  const float* Wbk = (const float*)d_in[4];
  const float* Wbr = (const float*)d_in[5];
  const float* bb_ = (const float*)d_in[6];
  float* out = (float*)d_out;

  char* ws = (char*)d_ws;
  // ws layout:
  //   xb    : 0          .. 33,554,432
  //   wkf   : 33,554,432 .. +4,194,304
  //   wrf   : 37,748,736 .. +4,194,304
  //   hring : 41,943,040 .. +1,048,576   (2 dir x 8 slots x 64 KiB, A-frag layout)
  unsigned short* xb   = (unsigned short*)(ws);
  unsigned short* wkf  = (unsigned short*)(ws + 33554432);
  unsigned short* wrf  = (unsigned short*)(ws + 37748736);
  unsigned short* hbuf = (unsigned short*)(ws + 41943040);

  // ring init: all sentinel bytes, then slot 0 of each direction = zeros (h(-1) = 0)
  hipMemsetAsync(ws + 41943040, 0x7f, 1048576, stream);
  hipMemsetAsync(ws + 41943040, 0x00, 65536, stream);            // dir 0, slot 0
  hipMemsetAsync(ws + 41943040 + 524288, 0x00, 65536, stream);   // dir 1, slot 0

  cast_x_kernel<<<8192, 256, 0, stream>>>(x, xb);
  swizzle_w_kernel<<<dim3(1024, 2), 256, 0, stream>>>(Wfk, Wfr, Wbk, Wbr, wkf, wrf);

  (void)hipFuncSetAttribute((const void*)lstm_main_kernel,
                            hipFuncAttributeMaxDynamicSharedMemorySize, 131072);
  lstm_main_kernel<<<dim3(GWG, 2), 256, 131072, stream>>>(xb, wkf, wrf, bf_, bb_, hbuf, out);
}

// Round 4
// 5989.585 us; speedup vs baseline: 1.0472x; 1.0472x over previous
//
#include <hip/hip_runtime.h>
#include <cstdint>
#include <cstddef>

#define Bsz 64
#define Tn  512
#define Dn  512
#define Hn  512
#define NG  2048        // 4*H
#define GWG 32          // workgroups per direction
#define NCOL 16         // h-columns per WG
#define SENTI 0x7f7f7f7fu   // bf16 0x7F7F = 3.3e38, impossible for |h|<=1

typedef __attribute__((ext_vector_type(8))) short short8;
typedef __attribute__((ext_vector_type(4))) float f32x4;
typedef __attribute__((ext_vector_type(4))) unsigned int u32x4;

union FragU { u32x4 v; short8 s; };

__device__ __forceinline__ unsigned short f2bf(float f) {
  union { float f; uint32_t u; } v; v.f = f;
  uint32_t u = v.u;
  uint32_t r = (u + 0x7fffu + ((u >> 16) & 1u)) >> 16;
  return (unsigned short)r;
}

__device__ __forceinline__ float sigm(float x) { return 1.0f / (1.0f + __expf(-x)); }
__device__ __forceinline__ float tanh_f(float x) { return 1.0f - 2.0f / (__expf(2.0f * x) + 1.0f); }

// ---------------- prep kernel 1: cast x fp32 -> bf16 ----------------
__global__ __launch_bounds__(256) void cast_x_kernel(const float* __restrict__ x,
                                                     unsigned short* __restrict__ xb) {
  size_t i = ((size_t)blockIdx.x * 256 + threadIdx.x) * 8;
  f32x4 a = *(const f32x4*)(x + i);
  f32x4 b = *(const f32x4*)(x + i + 4);
  short8 r;
  r[0] = (short)f2bf(a[0]); r[1] = (short)f2bf(a[1]);
  r[2] = (short)f2bf(a[2]); r[3] = (short)f2bf(a[3]);
  r[4] = (short)f2bf(b[0]); r[5] = (short)f2bf(b[1]);
  r[6] = (short)f2bf(b[2]); r[7] = (short)f2bf(b[3]);
  *(short8*)(xb + i) = r;
}

// ---------------- prep kernel 2: swizzle weights into MFMA B-fragment order ----------------
// frag layout (bf16): [dir(2)][wg(32)][nt(4)][kc(16)][lane(64)][j(8)]
//   n = nt*512 + wg*16 + (lane&15);  k = kc*32 + (lane>>4)*8 + j
__global__ __launch_bounds__(256) void swizzle_w_kernel(
    const float* __restrict__ Wfk, const float* __restrict__ Wfr,
    const float* __restrict__ Wbk, const float* __restrict__ Wbr,
    unsigned short* __restrict__ wkf, unsigned short* __restrict__ wrf)
{
  int idx = blockIdx.x * 256 + threadIdx.x;   // 0 .. 262143
  int arr  = blockIdx.y;                       // 0 = Wk, 1 = Wr
  int lane = idx & 63;
  int kc   = (idx >> 6) & 15;
  int nt   = (idx >> 10) & 3;
  int wg   = (idx >> 12) & 31;
  int dir  = (idx >> 17) & 1;
  const float* W = arr ? (dir ? Wbr : Wfr) : (dir ? Wbk : Wfk);
  unsigned short* dst = (arr ? wrf : wkf) + (size_t)idx * 8;
  int n  = nt * 512 + wg * NCOL + (lane & 15);
  int k0 = kc * 32 + ((lane >> 4) & 3) * 8;
#pragma unroll
  for (int j = 0; j < 8; ++j) dst[j] = f2bf(W[(size_t)(k0 + j) * NG + n]);
}

// ---------------- main persistent LSTM kernel (XCD-local cooperative) ----------------
// 1024 WGs launched; each reads its XCC_ID. First WG per XCD claims a direction
// (one dir per XCD, 2 XCDs win); first 32 WGs on a winning XCD take worker slots
// (1 WG/CU via 128 KiB LDS -> 32 workers = 32 CUs = one full XCD); rest exit.
// All h-ring traffic then stays in that XCD's L2: sc0 loads (L1 bypass, L2 hit),
// plain sc0 stores (L1 write-through). Sentinel data-as-flag ring as before.
// claims[] layout (ints): [0..7]=xcd_state (0 unknown, 1 pending, 2=dir0, 3=dir1,
// 9=no dir), [8]=dir_counter, [9],[10]=slot counters.
__global__ __launch_bounds__(256, 1) void lstm_main_kernel(
    const unsigned short* __restrict__ xb,
    const unsigned short* __restrict__ wkf,
    const unsigned short* __restrict__ wrf,
    const float* __restrict__ bias_f, const float* __restrict__ bias_b,
    unsigned short* __restrict__ hbuf,
    int* __restrict__ claims,
    float* __restrict__ out)
{
  const int tid  = threadIdx.x;
  const int lane = tid & 63;
  const int wv   = tid >> 6;       // wave id = m-tile (16 batch rows)
  const int quad = lane >> 4;
  const int col  = lane & 15;

  extern __shared__ char smem[];                  // 128 KiB dynamic
  short8* wr_lds = (short8*)smem;                 // 64 KiB Wr fragments
  short8* wk_lds = (short8*)(smem + 65536);       // 64 KiB Wk fragments

  // ---- XCD claim: resolve (dir, wg) or exit ----
  int xcd;
  asm volatile("s_getreg_b32 %0, hwreg(HW_REG_XCC_ID)" : "=s"(xcd));
  if (tid == 0) {
    int st = __hip_atomic_load(&claims[xcd], __ATOMIC_ACQUIRE, __HIP_MEMORY_SCOPE_AGENT);
    if (st == 0) {
      if (atomicCAS(&claims[xcd], 0, 1) == 0) {      // I'm this XCD's claim winner
        int d = atomicAdd(&claims[8], 1);
        st = (d < 2) ? (2 + d) : 9;
        __hip_atomic_store(&claims[xcd], st, __ATOMIC_RELEASE, __HIP_MEMORY_SCOPE_AGENT);
      }
    }
    while ((st = __hip_atomic_load(&claims[xcd], __ATOMIC_ACQUIRE, __HIP_MEMORY_SCOPE_AGENT)) < 2)
      __builtin_amdgcn_s_sleep(8);
    int role = -1;
    if (st != 9) {
      int dq = st - 2;
      int r = atomicAdd(&claims[9 + dq], 1);
      if (r < GWG) role = dq * GWG + r;
    }
    ((int*)smem)[0] = role;
  }
  __syncthreads();
  const int role = ((int*)smem)[0];
  __syncthreads();                 // everyone read role before smem is reused
  if (role < 0) return;            // not a worker
  const int wg  = role & 31;       // h-column slice
  const int dir = role >> 5;       // 0 fwd, 1 bwd

  {
    const short8* srcR = (const short8*)wrf + (size_t)(dir * GWG + wg) * 4096;
    const short8* srcK = (const short8*)wkf + (size_t)(dir * GWG + wg) * 4096;
    for (int i = tid; i < 4096; i += 256) { wr_lds[i] = srcR[i]; wk_lds[i] = srcK[i]; }
  }

  const float* bias = dir ? bias_b : bias_f;
  float bz[4];
#pragma unroll
  for (int g = 0; g < 4; ++g) bz[g] = bias[g * 512 + wg * NCOL + col];

  float cst[4] = {0.f, 0.f, 0.f, 0.f};

  const int am = wv * 16 + col;              // batch row for A-fragment loads
  unsigned short* ring = hbuf + (size_t)dir * (8 * 32768);   // 8 slots x 64 KiB

  // producer h-store constants (fragment-layout address for this lane's column pair)
  const int kcW = wg >> 1;
  const int c0  = col & ~1;
  const int qd2 = (((wg & 1) << 4) + c0) >> 3;   // k-quad of this column pair
  const int j2  = c0 & 7;
  const int r0  = (col & 1) << 1;                 // even lane stores r=0,1; odd r=2,3
  const int eBase = (((wv * 16 + kcW) * 64 + qd2 * 16 + quad * 4 + r0) * 8 + j2) >> 1;

  // x-row register prefetch (one step ahead; keeps the x-GEMM free of global loads)
  short8 xr[16];
  {
    const int tx0 = dir ? (Tn - 1) : 0;
    const short8* xrow = (const short8*)(xb + ((size_t)am * Tn + tx0) * Dn);
#pragma unroll
    for (int kc = 0; kc < 16; ++kc) xr[kc] = xrow[kc * 4 + quad];
  }

  __syncthreads();   // wr_lds/wk_lds ready (only barrier inside worker path)

// sc0 only: bypass L1, hit the XCD-local L2 (the coherence point for our workers)
#define HL(idx, base, offs) \
  asm volatile("global_load_dwordx4 %0, %1, off" offs " sc0" \
               : "=v"(hfr[idx].v) : "v"(base))
#define HISSUE() do { \
    const char* b0_ = hb; const char* b1_ = hb + 4096; \
    const char* b2_ = hb + 8192; const char* b3_ = hb + 12288; \
    HL(0,  b0_, "");               HL(1,  b0_, " offset:1024"); \
    HL(2,  b0_, " offset:2048");   HL(3,  b0_, " offset:3072"); \
    HL(4,  b1_, "");               HL(5,  b1_, " offset:1024"); \
    HL(6,  b1_, " offset:2048");   HL(7,  b1_, " offset:3072"); \
    HL(8,  b2_, "");               HL(9,  b2_, " offset:1024"); \
    HL(10, b2_, " offset:2048");   HL(11, b2_, " offset:3072"); \
    HL(12, b3_, "");               HL(13, b3_, " offset:1024"); \
    HL(14, b3_, " offset:2048");   HL(15, b3_, " offset:3072"); \
  } while (0)

  for (int t = 0; t < Tn; ++t) {
    const int tx = dir ? (Tn - 1 - t) : t;
    f32x4 a0 = {0.f,0.f,0.f,0.f}, a1 = {0.f,0.f,0.f,0.f};
    f32x4 a2 = {0.f,0.f,0.f,0.f}, a3 = {0.f,0.f,0.f,0.f};

    // ---- pre-issue this step's h loads (slot t&7 holds step t-1; slot 0 starts zeroed) ----
    FragU hfr[16];
    const char* hb = (const char*)ring + (size_t)(t & 7) * 65536
                   + ((size_t)(wv * 16) * 64 + lane) * 16;
    HISSUE();

    // ---- x-half (LDS weights + prefetched x regs: no global loads, overlaps h latency) ----
#pragma unroll 4
    for (int kc = 0; kc < 16; ++kc) {
      short8 a = xr[kc];
      a0 = __builtin_amdgcn_mfma_f32_16x16x32_bf16(a, wk_lds[(0*16+kc)*64 + lane], a0, 0,0,0);
      a1 = __builtin_amdgcn_mfma_f32_16x16x32_bf16(a, wk_lds[(1*16+kc)*64 + lane], a1, 0,0,0);
      a2 = __builtin_amdgcn_mfma_f32_16x16x32_bf16(a, wk_lds[(2*16+kc)*64 + lane], a2, 0,0,0);
      a3 = __builtin_amdgcn_mfma_f32_16x16x32_bf16(a, wk_lds[(3*16+kc)*64 + lane], a3, 0,0,0);
    }

    // ---- prefetch next step's x-row into registers (consumed next iteration) ----
    if (t < Tn - 1) {
      const int txn = dir ? (Tn - 2 - t) : (t + 1);
      const short8* xrow = (const short8*)(xb + ((size_t)am * Tn + txn) * Dn);
#pragma unroll
      for (int kc = 0; kc < 16; ++kc) xr[kc] = xrow[kc * 4 + quad];
    }

    // ---- sentinel poll: retry until every dword of every fragment is real h data ----
    for (;;) {
      asm volatile("s_waitcnt vmcnt(0)" ::: "memory");
      __builtin_amdgcn_sched_barrier(0);
      int ok = 1;
#pragma unroll
      for (int kc = 0; kc < 16; ++kc) {
        ok &= (hfr[kc].v[0] != SENTI);
        ok &= (hfr[kc].v[1] != SENTI);
        ok &= (hfr[kc].v[2] != SENTI);
        ok &= (hfr[kc].v[3] != SENTI);
      }
      if (__ballot(!ok) == 0ull) break;
      HISSUE();
    }

    // ---- h-half MFMAs (Wr from LDS; hfr already in registers from the poll) ----
#pragma unroll
    for (int kc = 0; kc < 16; ++kc) {
      short8 a = hfr[kc].s;
      a0 = __builtin_amdgcn_mfma_f32_16x16x32_bf16(a, wr_lds[(0*16+kc)*64 + lane], a0, 0,0,0);
      a1 = __builtin_amdgcn_mfma_f32_16x16x32_bf16(a, wr_lds[(1*16+kc)*64 + lane], a1, 0,0,0);
      a2 = __builtin_amdgcn_mfma_f32_16x16x32_bf16(a, wr_lds[(2*16+kc)*64 + lane], a2, 0,0,0);
      a3 = __builtin_amdgcn_mfma_f32_16x16x32_bf16(a, wr_lds[(3*16+kc)*64 + lane], a3, 0,0,0);
    }

    // ---- gates ----
    float hv[4];
#pragma unroll
    for (int r = 0; r < 4; ++r) {
      float zi = a0[r] + bz[0];
      float zf = a1[r] + bz[1];
      float zg = a2[r] + bz[2];
      float zo = a3[r] + bz[3];
      float ig = sigm(zi);
      float fg = sigm(zf);
      float gg = tanh_f(zg);
      float og = sigm(zo);
      float c  = fg * cst[r] + ig * gg;
      cst[r] = c;
      hv[r] = og * tanh_f(c);
    }

    // ---- publish h in fragment layout (pack column pair via one shfl_xor) ----
    // Plain sc0 stores: L1 is write-through, so the store is visible in the
    // XCD-local L2; consumers read with sc0 loads. The poll's vmcnt(0) above
    // (every step) drains last step's stores before these issue (ring safety).
    unsigned short hb16[4];
#pragma unroll
    for (int r = 0; r < 4; ++r) hb16[r] = f2bf(hv[r]);
    uint32_t msg = (col & 1) ? ((uint32_t)hb16[0] | ((uint32_t)hb16[1] << 16))
                             : ((uint32_t)hb16[2] | ((uint32_t)hb16[3] << 16));
    uint32_t got = (uint32_t)__shfl_xor((int)msg, 1);
    uint32_t pkA, pkB;
    if ((col & 1) == 0) {      // store r=0,1; mine is low (even col)
      pkA = (uint32_t)hb16[0] | ((got & 0xffffu) << 16);
      pkB = (uint32_t)hb16[1] | ((got >> 16) << 16);
    } else {                   // store r=2,3; partner is low
      pkA = (got & 0xffffu) | ((uint32_t)hb16[2] << 16);
      pkB = (got >> 16)     | ((uint32_t)hb16[3] << 16);
    }
    uint32_t* hc = (uint32_t*)((char*)ring + (size_t)((t + 1) & 7) * 65536);
    uint32_t* hx = (uint32_t*)((char*)ring + (size_t)((t + 5) & 7) * 65536);
    asm volatile("global_store_dword %0, %1, off sc0" :: "v"(hc + eBase),     "v"(pkA) : "memory");
    asm volatile("global_store_dword %0, %1, off sc0" :: "v"(hc + eBase + 4), "v"(pkB) : "memory");
    // re-sentinel slot (t+5)&7: destroys step t-4 data (all readers provably done),
    // arms the slot for step t+4's consumers. Same-lane same-address ordering vs the
    // future publish is guaranteed by the intervening poll vmcnt(0).
    {
      uint32_t sv = SENTI;
      asm volatile("global_store_dword %0, %1, off sc0" :: "v"(hx + eBase),     "v"(sv) : "memory");
      asm volatile("global_store_dword %0, %1, off sc0" :: "v"(hx + eBase + 4), "v"(sv) : "memory");
    }

    // ---- out stores (off critical path) ----
#pragma unroll
    for (int r = 0; r < 4; ++r) {
      const int b = wv * 16 + quad * 4 + r;
      out[((size_t)b * Tn + tx) * (2 * Hn) + dir * Hn + wg * NCOL + col] = hv[r];
      if (t == Tn - 1)
        out[(size_t)Bsz * Tn * (2 * Hn) + (size_t)b * (2 * Hn) + dir * Hn + wg * NCOL + col] = hv[r];
    }
  }
#undef HISSUE
#undef HL
}

// ---------------- launch ----------------
extern "C" void kernel_launch(void* const* d_in, const int* in_sizes, int n_in,
                              void* d_out, int out_size, void* d_ws, size_t ws_size,
                              hipStream_t stream) {
  const float* x   = (const float*)d_in[0];
  const float* Wfk = (const float*)d_in[1];
  const float* Wfr = (const float*)d_in[2];
  const float* bf_ = (const float*)d_in[3];
  const float* Wbk = (const float*)d_in[4];
  const float* Wbr = (const float*)d_in[5];
  const float* bb_ = (const float*)d_in[6];
  float* out = (float*)d_out;

  char* ws = (char*)d_ws;
  // ws layout:
  //   xb     : 0          .. 33,554,432
  //   wkf    : 33,554,432 .. +4,194,304
  //   wrf    : 37,748,736 .. +4,194,304
  //   hring  : 41,943,040 .. +1,048,576   (2 dir x 8 slots x 64 KiB, A-frag layout)
  //   claims : 42,991,616 .. +256         (xcd_state[8], dir_counter, slot_cnt[2])
  unsigned short* xb   = (unsigned short*)(ws);
  unsigned short* wkf  = (unsigned short*)(ws + 33554432);
  unsigned short* wrf  = (unsigned short*)(ws + 37748736);
  unsigned short* hbuf = (unsigned short*)(ws + 41943040);
  int*            clm  = (int*)           (ws + 42991616);

  // ring init: all sentinel bytes, then slot 0 of each direction = zeros (h(-1) = 0)
  hipMemsetAsync(ws + 41943040, 0x7f, 1048576, stream);
  hipMemsetAsync(ws + 41943040, 0x00, 65536, stream);            // dir 0, slot 0
  hipMemsetAsync(ws + 41943040 + 524288, 0x00, 65536, stream);   // dir 1, slot 0
  hipMemsetAsync(ws + 42991616, 0x00, 256, stream);              // claim state

  cast_x_kernel<<<8192, 256, 0, stream>>>(x, xb);
  swizzle_w_kernel<<<dim3(1024, 2), 256, 0, stream>>>(Wfk, Wfr, Wbk, Wbr, wkf, wrf);

  (void)hipFuncSetAttribute((const void*)lstm_main_kernel,
                            hipFuncAttributeMaxDynamicSharedMemorySize, 131072);
  lstm_main_kernel<<<dim3(1024), 256, 131072, stream>>>(xb, wkf, wrf, bf_, bb_, hbuf, clm, out);
}